// Round 3
// baseline (59689.746 us; speedup 1.0000x reference)
//
#include <hip/hip_runtime.h>

#define NN   2048
#define NBLK 256
#define TPB  256
#define CPB  8          // columns per block
#define SENT 1.0e30f    // finite "infinity" sentinel (fast-math-proof)

struct BFWS {
  float pub[2][NN];   // double-buffered published d vectors
  int   seq[NBLK];    // per-block publication counter
  int   flag;         // negative-cycle flag
};

__device__ __forceinline__ int ld_acq(int* p) {
  return __hip_atomic_load(p, __ATOMIC_ACQUIRE, __HIP_MEMORY_SCOPE_AGENT);
}
__device__ __forceinline__ unsigned ldp(unsigned* p) {
  return __hip_atomic_load(p, __ATOMIC_RELAXED, __HIP_MEMORY_SCOPE_AGENT);
}
__device__ __forceinline__ void stp(unsigned* p, unsigned v) {
  __hip_atomic_store(p, v, __ATOMIC_RELAXED, __HIP_MEMORY_SCOPE_AGENT);
}
__device__ __forceinline__ void st_rel(int* p, int v) {
  __hip_atomic_store(p, v, __ATOMIC_RELEASE, __HIP_MEMORY_SCOPE_AGENT);
}

__global__ void bf_init(BFWS* ws) {
  int t = threadIdx.x;
  if (t < NBLK) ws->seq[t] = 0;
  if (t == 0)   ws->flag   = 0;
}

__global__ void __launch_bounds__(TPB, 1)
bf_main(const float* __restrict__ A, const int* __restrict__ srcp,
        float* __restrict__ dist, float* __restrict__ pred,
        float* __restrict__ flagout, BFWS* ws) {
  const int tid = threadIdx.x;
  const int b   = blockIdx.x;
  const int c   = tid >> 5;       // column within block (0..7)
  const int s   = tid & 31;       // i-slice (0..31)
  const int col = b * CPB + c;
  const int src = srcp[0];

  __shared__ __align__(16) float d_lds[NN];
  __shared__ float red_v[CPB];
  __shared__ int   bflag;

  // ---- adjacency slice into registers: a[4k+m] = A[i][col], i = 4s+128k+m ----
  float a[64];
  #pragma unroll
  for (int k = 0; k < 16; ++k) {
    #pragma unroll
    for (int m = 0; m < 4; ++m) {
      int i = 4 * s + 128 * k + m;
      a[4 * k + m] = A[(size_t)i * NN + col];
    }
  }

  // ---- d0 into LDS (sentinel, not inf); write output column 0 ----
  #pragma unroll
  for (int h = 0; h < 2; ++h) {
    int e = 4 * tid + 1024 * h;
    float4 v;
    v.x = (e + 0 == src) ? 0.f : SENT;
    v.y = (e + 1 == src) ? 0.f : SENT;
    v.z = (e + 2 == src) ? 0.f : SENT;
    v.w = (e + 3 == src) ? 0.f : SENT;
    *reinterpret_cast<float4*>(&d_lds[e]) = v;
  }
  if (s == 0) {
    dist[(size_t)col * NN] = (col == src) ? 0.f : SENT;
    pred[(size_t)col * NN] = 0.f;
  }
  __syncthreads();

  for (int t = 1; t <= NN - 1; ++t) {
    if (t > 1) {
      // wait for all 256 publications of P_{t-1}; one thread per producer
      int* sq = &ws->seq[tid];
      while (ld_acq(sq) < t - 1) __builtin_amdgcn_s_sleep(1);
      __syncthreads();
      unsigned* pb = (unsigned*)ws->pub[(t - 1) & 1];
      #pragma unroll
      for (int h = 0; h < 2; ++h) {
        int e = 4 * tid + 1024 * h;
        float4 v;
        v.x = __uint_as_float(ldp(pb + e + 0));
        v.y = __uint_as_float(ldp(pb + e + 1));
        v.z = __uint_as_float(ldp(pb + e + 2));
        v.w = __uint_as_float(ldp(pb + e + 3));
        *reinterpret_cast<float4*>(&d_lds[e]) = v;
      }
      __syncthreads();
    }

    // ---- min-plus over this thread's 64 i's, 4 independent chains ----
    float bv0 = SENT * 2.f, bv1 = SENT * 2.f, bv2 = SENT * 2.f, bv3 = SENT * 2.f;
    int   bi0 = 0,          bi1 = 1,          bi2 = 2,          bi3 = 3;
    const float4* dq4 = reinterpret_cast<const float4*>(d_lds);
    #pragma unroll
    for (int k = 0; k < 16; ++k) {
      float4 dq = dq4[s + 32 * k];
      int base = 4 * s + 128 * k;
      float c0 = dq.x + a[4 * k + 0];
      float c1 = dq.y + a[4 * k + 1];
      float c2 = dq.z + a[4 * k + 2];
      float c3 = dq.w + a[4 * k + 3];
      if (c0 < bv0) { bv0 = c0; bi0 = base + 0; }
      if (c1 < bv1) { bv1 = c1; bi1 = base + 1; }
      if (c2 < bv2) { bv2 = c2; bi2 = base + 2; }
      if (c3 < bv3) { bv3 = c3; bi3 = base + 3; }
    }
    // merge chains with first-index tie-break
    float bv = bv0; int bi = bi0;
    if (bv1 < bv || (bv1 == bv && bi1 < bi)) { bv = bv1; bi = bi1; }
    if (bv2 < bv || (bv2 == bv && bi2 < bi)) { bv = bv2; bi = bi2; }
    if (bv3 < bv || (bv3 == bv && bi3 < bi)) { bv = bv3; bi = bi3; }
    // reduce across the 32 lanes of this column group
    #pragma unroll
    for (int off = 16; off; off >>= 1) {
      float ov = __shfl_xor(bv, off, 32);
      int   oi = __shfl_xor(bi, off, 32);
      if (ov < bv || (ov == bv && oi < bi)) { bv = ov; bi = oi; }
    }

    if (s == 0) {
      dist[(size_t)col * NN + t] = bv;       // always finite (<= SENT)
      pred[(size_t)col * NN + t] = (float)bi;
      red_v[c] = bv;
    }
    __syncthreads();           // red_v visible; all d_lds reads of this step done
    if (tid == 0) {
      unsigned* pb = (unsigned*)ws->pub[t & 1];
      #pragma unroll
      for (int cc = 0; cc < CPB; ++cc)
        stp(pb + b * CPB + cc, __float_as_uint(red_v[cc]));
      st_rel(&ws->seq[b], t);  // release: pub stores ordered before
    }
  }

  // ---- negative-cycle check on P_{NN-1} ----
  {
    int* sq = &ws->seq[tid];
    while (ld_acq(sq) < NN - 1) __builtin_amdgcn_s_sleep(1);
    __syncthreads();
    unsigned* pb = (unsigned*)ws->pub[(NN - 1) & 1];
    #pragma unroll
    for (int h = 0; h < 2; ++h) {
      int e = 4 * tid + 1024 * h;
      float4 v;
      v.x = __uint_as_float(ldp(pb + e + 0));
      v.y = __uint_as_float(ldp(pb + e + 1));
      v.z = __uint_as_float(ldp(pb + e + 2));
      v.w = __uint_as_float(ldp(pb + e + 3));
      *reinterpret_cast<float4*>(&d_lds[e]) = v;
    }
    if (tid == 0) bflag = 0;
    __syncthreads();
    float dj = d_lds[col];
    int viol = 0;
    const float4* dq4 = reinterpret_cast<const float4*>(d_lds);
    #pragma unroll
    for (int k = 0; k < 16; ++k) {
      float4 dq = dq4[s + 32 * k];
      viol |= (dq.x + a[4 * k + 0] < dj);
      viol |= (dq.y + a[4 * k + 1] < dj);
      viol |= (dq.z + a[4 * k + 2] < dj);
      viol |= (dq.w + a[4 * k + 3] < dj);
    }
    if (viol) bflag = 1;
    __syncthreads();
    if (tid == 0) {
      if (bflag) atomicOr(&ws->flag, 1);   // device-scope
      st_rel(&ws->seq[b], NN);
    }
  }
  if (b == 0) {
    int* sq = &ws->seq[tid];
    while (ld_acq(sq) < NN) __builtin_amdgcn_s_sleep(1);
    __syncthreads();
    if (tid == 0) {
      int f = __hip_atomic_load(&ws->flag, __ATOMIC_ACQUIRE, __HIP_MEMORY_SCOPE_AGENT);
      flagout[0] = f ? 1.f : 0.f;
    }
  }
}

extern "C" void kernel_launch(void* const* d_in, const int* in_sizes, int n_in,
                              void* d_out, int out_size, void* d_ws, size_t ws_size,
                              hipStream_t stream) {
  (void)in_sizes; (void)n_in; (void)out_size; (void)ws_size;
  const float* A    = (const float*)d_in[0];
  const int*   srcp = (const int*)d_in[1];
  float* dist    = (float*)d_out;
  float* pred    = dist + (size_t)NN * NN;
  float* flagout = dist + (size_t)2 * NN * NN;
  BFWS*  ws      = (BFWS*)d_ws;

  bf_init<<<1, 256, 0, stream>>>(ws);
  bf_main<<<dim3(NBLK), dim3(TPB), 0, stream>>>(A, srcp, dist, pred, flagout, ws);
}

// Round 5
// 15581.487 us; speedup vs baseline: 3.8308x; 3.8308x over previous
//
#include <hip/hip_runtime.h>

#define NN   2048
#define NBLK 256
#define TPB  256
#define CPB  8          // columns per block
#define SENT 1.0e30f    // finite "infinity" sentinel (fast-math-proof)

struct BFWS {
  float pub[2][NN];   // double-buffered published d vectors
  int   seq[NBLK];    // per-block publication counter
  int   flag;         // negative-cycle flag
};

// All cross-block communication uses RELAXED agent-scope atomics (sc1 -> LLC,
// no buffer_inv storms). Producer-side ordering via explicit s_waitcnt vmcnt(0).
__device__ __forceinline__ int ldr(int* p) {
  return __hip_atomic_load(p, __ATOMIC_RELAXED, __HIP_MEMORY_SCOPE_AGENT);
}
__device__ __forceinline__ void str(int* p, int v) {
  __hip_atomic_store(p, v, __ATOMIC_RELAXED, __HIP_MEMORY_SCOPE_AGENT);
}
__device__ __forceinline__ unsigned ldp(unsigned* p) {
  return __hip_atomic_load(p, __ATOMIC_RELAXED, __HIP_MEMORY_SCOPE_AGENT);
}
__device__ __forceinline__ void stp(unsigned* p, unsigned v) {
  __hip_atomic_store(p, v, __ATOMIC_RELAXED, __HIP_MEMORY_SCOPE_AGENT);
}
__device__ __forceinline__ void wait_vm0() {
  asm volatile("s_waitcnt vmcnt(0)" ::: "memory");
}

__global__ void bf_init(BFWS* ws) {
  int t = threadIdx.x;
  if (t < NBLK) ws->seq[t] = 0;
  if (t == 0)   ws->flag   = 0;
}

// Wave 0 polls all 256 seq words (4 per lane) until every block reached tgt.
__device__ __forceinline__ void wait_all(BFWS* ws, int tid, int tgt) {
  if (tid < 64) {
    int* sq = ws->seq + tid * 4;
    for (;;) {
      int s0 = ldr(sq + 0), s1 = ldr(sq + 1);
      int s2 = ldr(sq + 2), s3 = ldr(sq + 3);
      int ok = (s0 >= tgt) & (s1 >= tgt) & (s2 >= tgt) & (s3 >= tgt);
      if (__all(ok)) break;
      __builtin_amdgcn_s_sleep(1);
    }
  }
  asm volatile("" ::: "memory");
  __syncthreads();   // everyone waits for wave 0's verdict
}

__global__ void __launch_bounds__(TPB, 1)
bf_main(const float* __restrict__ A, const int* __restrict__ srcp,
        float* __restrict__ dist, float* __restrict__ pred,
        float* __restrict__ flagout, BFWS* ws) {
  const int tid = threadIdx.x;
  const int b   = blockIdx.x;
  const int c   = tid >> 5;       // column within block (0..7)
  const int s   = tid & 31;       // i-slice (0..31)
  const int col = b * CPB + c;
  const int src = srcp[0];

  __shared__ __align__(16) float d_lds[NN];
  __shared__ int bflag;

  // ---- adjacency slice into registers: a[4k+m] = A[i][col], i = 4s+128k+m ----
  float a[64];
  #pragma unroll
  for (int k = 0; k < 16; ++k) {
    #pragma unroll
    for (int m = 0; m < 4; ++m) {
      int i = 4 * s + 128 * k + m;
      a[4 * k + m] = A[(size_t)i * NN + col];
    }
  }

  // ---- d0 into LDS (finite sentinel); write output column 0 ----
  #pragma unroll
  for (int h = 0; h < 2; ++h) {
    int e = 4 * tid + 1024 * h;
    float4 v;
    v.x = (e + 0 == src) ? 0.f : SENT;
    v.y = (e + 1 == src) ? 0.f : SENT;
    v.z = (e + 2 == src) ? 0.f : SENT;
    v.w = (e + 3 == src) ? 0.f : SENT;
    *reinterpret_cast<float4*>(&d_lds[e]) = v;
  }
  if (s == 0) {
    dist[(size_t)col * NN] = (col == src) ? 0.f : SENT;
    pred[(size_t)col * NN] = 0.f;
  }
  __syncthreads();

  for (int t = 1; t <= NN - 1; ++t) {
    if (t > 1) {
      wait_all(ws, tid, t - 1);
      // stage published d vector into LDS (relaxed LLC loads, coalesced)
      unsigned* pb = (unsigned*)ws->pub[(t - 1) & 1];
      #pragma unroll
      for (int h = 0; h < 8; ++h) {
        int e = h * TPB + tid;
        d_lds[e] = __uint_as_float(ldp(pb + e));
      }
      __syncthreads();
    }

    // ---- min-plus over this thread's 64 i's, 4 independent chains ----
    float bv0 = SENT * 2.f, bv1 = SENT * 2.f, bv2 = SENT * 2.f, bv3 = SENT * 2.f;
    int   bi0 = 0,          bi1 = 1,          bi2 = 2,          bi3 = 3;
    const float4* dq4 = reinterpret_cast<const float4*>(d_lds);
    #pragma unroll
    for (int k = 0; k < 16; ++k) {
      float4 dq = dq4[s + 32 * k];
      int base = 4 * s + 128 * k;
      float c0 = dq.x + a[4 * k + 0];
      float c1 = dq.y + a[4 * k + 1];
      float c2 = dq.z + a[4 * k + 2];
      float c3 = dq.w + a[4 * k + 3];
      if (c0 < bv0) { bv0 = c0; bi0 = base + 0; }
      if (c1 < bv1) { bv1 = c1; bi1 = base + 1; }
      if (c2 < bv2) { bv2 = c2; bi2 = base + 2; }
      if (c3 < bv3) { bv3 = c3; bi3 = base + 3; }
    }
    // merge chains with first-index tie-break
    float bv = bv0; int bi = bi0;
    if (bv1 < bv || (bv1 == bv && bi1 < bi)) { bv = bv1; bi = bi1; }
    if (bv2 < bv || (bv2 == bv && bi2 < bi)) { bv = bv2; bi = bi2; }
    if (bv3 < bv || (bv3 == bv && bi3 < bi)) { bv = bv3; bi = bi3; }
    // butterfly across the 32 lanes of this column group (all lanes get result)
    #pragma unroll
    for (int off = 16; off; off >>= 1) {
      float ov = __shfl_xor(bv, off, 32);
      int   oi = __shfl_xor(bi, off, 32);
      if (ov < bv || (ov == bv && oi < bi)) { bv = ov; bi = oi; }
    }

    if (s == 1) {                     // outputs off the publisher lane
      dist[(size_t)col * NN + t] = bv;
      pred[(size_t)col * NN + t] = (float)bi;
    }
    if (s == 0) {                     // publish this column's new d
      stp((unsigned*)ws->pub[t & 1] + col, __float_as_uint(bv));
    }
    wait_vm0();                       // pub stores at LLC before seq store
    __syncthreads();                  // all 8 columns published
    if (tid == 0) str(&ws->seq[b], t);
  }

  // ---- negative-cycle check on P_{NN-1} ----
  {
    wait_all(ws, tid, NN - 1);
    unsigned* pb = (unsigned*)ws->pub[(NN - 1) & 1];
    #pragma unroll
    for (int h = 0; h < 8; ++h) {
      int e = h * TPB + tid;
      d_lds[e] = __uint_as_float(ldp(pb + e));
    }
    if (tid == 0) bflag = 0;
    __syncthreads();
    float dj = d_lds[col];
    int viol = 0;
    const float4* dq4 = reinterpret_cast<const float4*>(d_lds);
    #pragma unroll
    for (int k = 0; k < 16; ++k) {
      float4 dq = dq4[s + 32 * k];
      viol |= (dq.x + a[4 * k + 0] < dj);
      viol |= (dq.y + a[4 * k + 1] < dj);
      viol |= (dq.z + a[4 * k + 2] < dj);
      viol |= (dq.w + a[4 * k + 3] < dj);
    }
    if (viol) bflag = 1;
    __syncthreads();
    if (tid == 0) {
      if (bflag) atomicOr(&ws->flag, 1);   // device-scope RMW at LLC
      wait_vm0();
      str(&ws->seq[b], NN);
    }
  }
  if (b == 0) {
    wait_all(ws, tid, NN);
    if (tid == 0) {
      int f = ldr(&ws->flag);
      flagout[0] = f ? 1.f : 0.f;
    }
  }
}

extern "C" void kernel_launch(void* const* d_in, const int* in_sizes, int n_in,
                              void* d_out, int out_size, void* d_ws, size_t ws_size,
                              hipStream_t stream) {
  (void)in_sizes; (void)n_in; (void)out_size; (void)ws_size;
  const float* A    = (const float*)d_in[0];
  const int*   srcp = (const int*)d_in[1];
  float* dist    = (float*)d_out;
  float* pred    = dist + (size_t)NN * NN;
  float* flagout = dist + (size_t)2 * NN * NN;
  BFWS*  ws      = (BFWS*)d_ws;

  bf_init<<<1, 256, 0, stream>>>(ws);
  bf_main<<<dim3(NBLK), dim3(TPB), 0, stream>>>(A, srcp, dist, pred, flagout, ws);
}

// Round 8
// 7647.279 us; speedup vs baseline: 7.8054x; 2.0375x over previous
//
#include <hip/hip_runtime.h>

#define NN   2048
#define NBLK 256
#define TPB  256
#define CPB  8          // columns per block
#define SENT 1.0e30f    // finite "infinity" sentinel (fast-math-proof)

typedef unsigned long long u64;

struct BFWS {
  u64 pub[2][NN];    // (tag<<32)|fp32bits, double-buffered by round parity
  u64 cyc[NBLK];     // (tag NN<<32)|viol  for the negative-cycle gather
};

// Relaxed agent-scope atomics: sc-bit loads/stores that bypass L0/L1 and are
// serviced at the device coherence point; no buffer_inv, no waitcnt fences.
// The 8-byte store is single-copy atomic, so tag+value publish in ONE hop.
__device__ __forceinline__ u64 ld64(u64* p) {
  return __hip_atomic_load(p, __ATOMIC_RELAXED, __HIP_MEMORY_SCOPE_AGENT);
}
__device__ __forceinline__ void st64(u64* p, u64 v) {
  __hip_atomic_store(p, v, __ATOMIC_RELAXED, __HIP_MEMORY_SCOPE_AGENT);
}

__global__ void bf_init(BFWS* ws) {
  int t = threadIdx.x;
  if (t < NBLK) ws->cyc[t] = 0ull;   // tag 0: never matches (rounds are >=1)
}

__global__ void __launch_bounds__(TPB, 1)
bf_main(const float* __restrict__ A, const int* __restrict__ srcp,
        float* __restrict__ dist, float* __restrict__ pred,
        float* __restrict__ flagout, BFWS* ws) {
  const int tid = threadIdx.x;
  const int b   = blockIdx.x;
  const int c   = tid >> 5;       // column within block (0..7)
  const int s   = tid & 31;       // i-slice (0..31)
  const int col = b * CPB + c;
  const int src = srcp[0];

  __shared__ __align__(16) float d_lds[2][NN];   // double-buffered d vector
  __shared__ int bflag;
  __shared__ int wv[4];

  // ---- adjacency slice into registers: a[4k+m] = A[i][col], i = 4s+128k+m ----
  float a[64];
  #pragma unroll
  for (int k = 0; k < 16; ++k) {
    #pragma unroll
    for (int m = 0; m < 4; ++m) {
      int i = 4 * s + 128 * k + m;
      a[4 * k + m] = A[(size_t)i * NN + col];
    }
  }

  // ---- d0 into LDS buffer 0 (round 1 reads buf[(1-1)&1] = buf[0]) ----
  #pragma unroll
  for (int h = 0; h < 8; ++h) {
    int e = h * TPB + tid;
    d_lds[0][e] = (e == src) ? 0.f : SENT;
  }
  if (s == 0) {
    dist[(size_t)col * NN] = (col == src) ? 0.f : SENT;
    pred[(size_t)col * NN] = 0.f;
  }
  __syncthreads();

  for (int t = 1; t <= NN - 1; ++t) {
    if (t > 1) {
      // ---- poll+stage round t-1: each thread owns 8 tagged words ----
      u64* pb = ws->pub[(t - 1) & 1];
      const unsigned want = (unsigned)(t - 1);
      u64 v[8];
      unsigned got = 0;
      while (got != 0xFFu) {
        #pragma unroll
        for (int h = 0; h < 8; ++h)
          if (!((got >> h) & 1)) v[h] = ld64(pb + h * TPB + tid);
        #pragma unroll
        for (int h = 0; h < 8; ++h)
          if (!((got >> h) & 1) && (unsigned)(v[h] >> 32) == want) got |= 1u << h;
        if (got != 0xFFu) __builtin_amdgcn_s_sleep(1);
      }
      #pragma unroll
      for (int h = 0; h < 8; ++h)
        d_lds[(t - 1) & 1][h * TPB + tid] = __uint_as_float((unsigned)v[h]);
      __syncthreads();   // single barrier per round (buffer-safety by parity)
    }

    // ---- min-plus over this thread's 64 i's, 4 independent chains ----
    float bv0 = SENT * 2.f, bv1 = SENT * 2.f, bv2 = SENT * 2.f, bv3 = SENT * 2.f;
    int   bi0 = 0,          bi1 = 1,          bi2 = 2,          bi3 = 3;
    const float4* dq4 = reinterpret_cast<const float4*>(d_lds[(t - 1) & 1]);
    #pragma unroll
    for (int k = 0; k < 16; ++k) {
      float4 dq = dq4[s + 32 * k];
      int base = 4 * s + 128 * k;
      float c0 = dq.x + a[4 * k + 0];
      float c1 = dq.y + a[4 * k + 1];
      float c2 = dq.z + a[4 * k + 2];
      float c3 = dq.w + a[4 * k + 3];
      if (c0 < bv0) { bv0 = c0; bi0 = base + 0; }
      if (c1 < bv1) { bv1 = c1; bi1 = base + 1; }
      if (c2 < bv2) { bv2 = c2; bi2 = base + 2; }
      if (c3 < bv3) { bv3 = c3; bi3 = base + 3; }
    }
    // merge chains with first-index tie-break
    float bv = bv0; int bi = bi0;
    if (bv1 < bv || (bv1 == bv && bi1 < bi)) { bv = bv1; bi = bi1; }
    if (bv2 < bv || (bv2 == bv && bi2 < bi)) { bv = bv2; bi = bi2; }
    if (bv3 < bv || (bv3 == bv && bi3 < bi)) { bv = bv3; bi = bi3; }
    // butterfly across the 32 lanes of this column group
    #pragma unroll
    for (int off = 16; off; off >>= 1) {
      float ov = __shfl_xor(bv, off, 32);
      int   oi = __shfl_xor(bi, off, 32);
      if (ov < bv || (ov == bv && oi < bi)) { bv = ov; bi = oi; }
    }

    // publish FIRST (critical path): one 8B atomic = tag + value
    if (s == 0)
      st64(&ws->pub[t & 1][col], ((u64)(unsigned)t << 32) | (u64)__float_as_uint(bv));
    if (s == 1) {                     // outputs off the publisher lane
      dist[(size_t)col * NN + t] = bv;
      pred[(size_t)col * NN + t] = (float)bi;
    }
  }

  // ---- negative-cycle check on P_{NN-1} (slot (NN-1)&1 = 1) ----
  {
    u64* pb = ws->pub[(NN - 1) & 1];
    const unsigned want = (unsigned)(NN - 1);
    u64 v[8];
    unsigned got = 0;
    while (got != 0xFFu) {
      #pragma unroll
      for (int h = 0; h < 8; ++h)
        if (!((got >> h) & 1)) v[h] = ld64(pb + h * TPB + tid);
      #pragma unroll
      for (int h = 0; h < 8; ++h)
        if (!((got >> h) & 1) && (unsigned)(v[h] >> 32) == want) got |= 1u << h;
      if (got != 0xFFu) __builtin_amdgcn_s_sleep(1);
    }
    #pragma unroll
    for (int h = 0; h < 8; ++h)
      d_lds[1][h * TPB + tid] = __uint_as_float((unsigned)v[h]);
    if (tid == 0) bflag = 0;
    __syncthreads();

    float dj = d_lds[1][col];
    int viol = 0;
    const float4* dq4 = reinterpret_cast<const float4*>(d_lds[1]);
    #pragma unroll
    for (int k = 0; k < 16; ++k) {
      float4 dq = dq4[s + 32 * k];
      viol |= (dq.x + a[4 * k + 0] < dj);
      viol |= (dq.y + a[4 * k + 1] < dj);
      viol |= (dq.z + a[4 * k + 2] < dj);
      viol |= (dq.w + a[4 * k + 3] < dj);
    }
    if (viol) bflag = 1;      // benign same-value race within block
    __syncthreads();
    if (tid == 0)
      st64(&ws->cyc[b], ((u64)(unsigned)NN << 32) | (u64)(unsigned)bflag);
  }

  // ---- block 0 gathers the 256 tagged viol bits and writes the flag ----
  if (b == 0) {
    u64 w;
    do {
      w = ld64(&ws->cyc[tid]);
      if ((unsigned)(w >> 32) == (unsigned)NN) break;
      __builtin_amdgcn_s_sleep(1);
    } while (true);
    int myv = (int)((unsigned)w & 1u);
    int anyv = __any(myv);
    if ((tid & 63) == 0) wv[tid >> 6] = anyv;
    __syncthreads();
    if (tid == 0)
      flagout[0] = (wv[0] | wv[1] | wv[2] | wv[3]) ? 1.f : 0.f;
  }
}

extern "C" void kernel_launch(void* const* d_in, const int* in_sizes, int n_in,
                              void* d_out, int out_size, void* d_ws, size_t ws_size,
                              hipStream_t stream) {
  (void)in_sizes; (void)n_in; (void)out_size; (void)ws_size;
  const float* A    = (const float*)d_in[0];
  const int*   srcp = (const int*)d_in[1];
  float* dist    = (float*)d_out;
  float* pred    = dist + (size_t)NN * NN;
  float* flagout = dist + (size_t)2 * NN * NN;
  BFWS*  ws      = (BFWS*)d_ws;

  bf_init<<<1, 256, 0, stream>>>(ws);
  bf_main<<<dim3(NBLK), dim3(TPB), 0, stream>>>(A, srcp, dist, pred, flagout, ws);
}